// Round 2
// baseline (256.388 us; speedup 1.0000x reference)
//
#include <hip/hip_runtime.h>

// z[b,d] = x[b,d] * (1 + sum_{i=1..K} w[i-1,d] * x[b,(d+i) mod D])
// B=8192, D=4096, K=16, fp32. HBM-bound: ideal ~268 MB -> ~43 us floor.
//
// R1 lesson: __launch_bounds__(256,4) VGPR clamp -> spills -> 900 MB scratch.
// R2 (prev best, 86 us/dispatch): LDS burst-stage + __syncthreads. Counters
// showed Occupancy 18.6%, VALUBusy 16.7%, HBM 30% -> latency-bound: the
// barrier drains vmcnt(0), so no loads are in flight during compute.
// R3: barrier-free. Each thread needs only 20 consecutive floats =
// 5 overlapping float4 loads (each wave-coalesced; 4/5 overlap hits L1).
// Register ping-pong prefetch keeps next row's 5 loads in flight under the
// current row's FMAs -> counted s_waitcnt vmcnt(N) instead of a drain.
// No LDS -> no barrier, no halo, no bank conflicts. nt stores keep x in L3.
// R3 compile fix: __builtin_nontemporal_store needs a NATIVE vector type,
// not HIP's float4 class -> store via ext_vector_type(4) alias.

#define D 4096
#define DG 1024          // D/4 float4 column-groups per row
#define K 16
#define TPB 256
#define RPB 16           // rows per block -> grid (4, 512) = 2048 blocks

typedef float f32x4 __attribute__((ext_vector_type(4)));

__global__ __launch_bounds__(TPB) void quad_enhancer_kernel(
    const float* __restrict__ x, const float* __restrict__ w,
    float* __restrict__ out) {
  const int tid = threadIdx.x;
  const int cg = blockIdx.x * TPB + tid;  // this thread's column-group
  const int b0 = blockIdx.y * RPB;

  const float4* __restrict__ x4 = (const float4*)x;
  const float4* __restrict__ w4 = (const float4*)w;
  f32x4* __restrict__ out4 = (f32x4*)out;

  // Neighbor groups with wrap (only cg >= DG-4 actually wraps).
  const int g1 = (cg + 1) & (DG - 1);
  const int g2 = (cg + 2) & (DG - 1);
  const int g3 = (cg + 3) & (DG - 1);
  const int g4 = (cg + 4) & (DG - 1);

  // w[:, 4cg..4cg+3] in 64 VGPRs, reused for all RPB rows (L2-hot, 256 KB).
  float4 wv[K];
#pragma unroll
  for (int i = 0; i < K; ++i) wv[i] = w4[i * DG + cg];

  auto loadrow = [&](int b, float4* buf) {
    const float4* __restrict__ xr = x4 + (size_t)b * DG;
    buf[0] = xr[cg];
    buf[1] = xr[g1];
    buf[2] = xr[g2];
    buf[3] = xr[g3];
    buf[4] = xr[g4];
  };

  auto compute_store = [&](int b, const float4* buf) {
    float xs[20];
#pragma unroll
    for (int j = 0; j < 5; ++j) {  // static indexing only -> stays in VGPRs
      xs[4 * j + 0] = buf[j].x;
      xs[4 * j + 1] = buf[j].y;
      xs[4 * j + 2] = buf[j].z;
      xs[4 * j + 3] = buf[j].w;
    }
    float ax = 1.0f, ay = 1.0f, az = 1.0f, aw = 1.0f;
#pragma unroll
    for (int i = 0; i < K; ++i) {
      ax = fmaf(wv[i].x, xs[i + 1], ax);
      ay = fmaf(wv[i].y, xs[i + 2], ay);
      az = fmaf(wv[i].z, xs[i + 3], az);
      aw = fmaf(wv[i].w, xs[i + 4], aw);
    }
    f32x4 o;
    o.x = xs[0] * ax;
    o.y = xs[1] * ay;
    o.z = xs[2] * az;
    o.w = xs[3] * aw;
    __builtin_nontemporal_store(o, &out4[(size_t)b * DG + cg]);
  };

  // Software pipeline over rows: ping-pong register buffers, depth 1.
  float4 bufA[5], bufB[5];
  loadrow(b0, bufA);
#pragma unroll 1
  for (int r = 0; r < RPB; r += 2) {
    loadrow(b0 + r + 1, bufB);      // in flight under bufA's compute
    compute_store(b0 + r, bufA);
    if (r + 2 < RPB) loadrow(b0 + r + 2, bufA);  // in flight under bufB
    compute_store(b0 + r + 1, bufB);
  }
}

extern "C" void kernel_launch(void* const* d_in, const int* in_sizes, int n_in,
                              void* d_out, int out_size, void* d_ws, size_t ws_size,
                              hipStream_t stream) {
  const float* x = (const float*)d_in[0];
  const float* w = (const float*)d_in[1];
  float* out = (float*)d_out;
  const int B = in_sizes[0] / D;  // 8192

  dim3 grid(DG / TPB, B / RPB);   // (4, 512) = 2048 blocks
  quad_enhancer_kernel<<<grid, TPB, 0, stream>>>(x, w, out);
}